// Round 4
// baseline (1377.977 us; speedup 1.0000x reference)
//
#include <hip/hip_runtime.h>
#include <hip/hip_bf16.h>

// Sizes: T=256, B=2048, NC=3, NM=125, IN=128, H=256, 4H=1024, K_gates=384
// 256 WGs x 512 thr. WG = (s = h-col slice 0..7, r = row block 0..31), rows [64r,64r+64).
// TRANSPOSED GEMMs, all weights in VGPRs (gate slice A-frags / out-proj A-frags).
// NEW: producer/consumer wave specialization + 2-sub-block software pipeline.
//   waves 0-3 (gw): gates MFMA -> LSTM -> coherent h-store -> flag   for sub-block PA
//   waves 4-7 (ow): poll flag -> coherent h-restage -> out-proj -> epilogue for PB=PA^1
//   Sub-blocks alternate each slot (2 slots per timestep), so the h-exchange round
//   trip of one sub-block hides under the other sub-block's compute.
constexpr int TSTEPS = 255;
constexpr int XROW   = 392;   // LDS x|h row stride (shorts): [x 0..127 | h 128..383] + 8 pad

typedef __attribute__((ext_vector_type(8))) short short8;
typedef __attribute__((ext_vector_type(4))) float f32x4;
typedef __attribute__((ext_vector_type(16))) float f32x16;
typedef __attribute__((ext_vector_type(4))) int i32x4;
typedef __attribute__((ext_vector_type(2))) unsigned int u32x2;

__device__ __forceinline__ unsigned short f2bf(float f) {
    __hip_bfloat16 h = __float2bfloat16(f);
    return *reinterpret_cast<unsigned short*>(&h);
}
__device__ __forceinline__ float bf2f(unsigned short u) {
    __hip_bfloat16 h;
    *reinterpret_cast<unsigned short*>(&h) = u;
    return __bfloat162float(h);
}
__device__ __forceinline__ float sigf(float x) {
    return __builtin_amdgcn_rcpf(1.f + __expf(-x));
}
__device__ __forceinline__ float tanh_fast(float x) {
    x = fminf(fmaxf(x, -15.f), 15.f);
    float e = __expf(-2.f * x);
    return (1.f - e) * __builtin_amdgcn_rcpf(1.f + e);
}

// Coherent (cross-XCD) accesses: sc0 sc1 bypass non-coherent caches.
__device__ __forceinline__ i32x4 load_coh16(const void* p) {
    i32x4 r;
    asm volatile("global_load_dwordx4 %0, %1, off sc0 sc1" : "=v"(r) : "v"(p) : "memory");
    return r;
}
__device__ __forceinline__ void store_coh16(void* p, i32x4 v) {
    asm volatile("global_store_dwordx4 %0, %1, off sc0 sc1" :: "v"(p), "v"(v) : "memory");
}

// ---------------------------------------------------------------------------
// Prep: pack weights to bf16 MFMA A-fragment order; fuse biases; zero flags.
// (unchanged from round 3)
// ---------------------------------------------------------------------------
__global__ void prep_kernel(const float* __restrict__ Wih, const float* __restrict__ Whh,
                            const float* __restrict__ bih, const float* __restrict__ bhh,
                            const float* __restrict__ Wcat, const float* __restrict__ bcat,
                            const float* __restrict__ Wval, const float* __restrict__ bval,
                            unsigned short* __restrict__ Wg, unsigned short* __restrict__ Wo,
                            float* __restrict__ bg, float* __restrict__ bo,
                            unsigned int* __restrict__ flags) {
    int idx = blockIdx.x * 256 + threadIdx.x;
    if (idx < 393216) {
        int j   = idx & 7;
        int l   = (idx >> 3) & 63;
        int t24 = idx >> 9;
        int kt  = t24 % 24;
        int u   = t24 / 24;            // s*4 + gm
        int gm = u & 3, ss = u >> 2;
        int pm = l & 31;
        int n  = (pm & 3) * 256 + ss * 32 + gm * 8 + (pm >> 2);
        int k  = kt * 16 + (l >> 5) * 8 + j;
        float v = (k < 128) ? Wih[n * 128 + k] : Whh[n * 256 + (k - 128)];
        Wg[idx] = f2bf(v);
    } else if (idx < 425984) {
        int i2 = idx - 393216;
        int j = i2 & 7, ll = (i2 >> 3) & 63, kt = (i2 >> 9) & 15, om = i2 >> 13;
        int n = om * 32 + (ll & 31);
        int k = kt * 16 + (ll >> 5) * 8 + j;
        float v = (n < 3) ? Wcat[n * 256 + k] : Wval[(n - 3) * 256 + k];
        Wo[i2] = f2bf(v);
    } else if (idx < 427008) {
        int i3 = idx - 425984;
        bg[i3] = bih[i3] + bhh[i3];
    } else if (idx < 427136) {
        int i4 = idx - 427008;
        bo[i4] = (i4 < 3) ? bcat[i4] : bval[i4 - 3];
    } else if (idx < 428160) {
        flags[idx - 427136] = 0u;      // barrier counters (re-zeroed every launch/replay)
    }
}

// ---------------------------------------------------------------------------
// One pipeline slot. PA = gate-wave sub-block (compile-time), PB = out-wave
// sub-block. TG = gate step, TO = out step. CSTA = c-state array for PA,
// XVB = reg-resident x for PB. Two WG barriers per slot (mid + boundary).
// ---------------------------------------------------------------------------
#define SLOT(PA, TG, TO, CSTA, XVB) do {                                            \
    constexpr int PB_ = (PA) ^ 1;                                                   \
    const int tg_ = (TG), to_ = (TO);                                               \
    const bool gact = isGW && (tg_ < TSTEPS);                                       \
    const bool oact = (!isGW) && (to_ >= 0);                                        \
    f32x16 acc, accB;                                                               \
    f32x4 sq[4];                                                                    \
    /* ---- phase 1: gw MFMA(PA)  ||  ow prefetch+poll+restage(PB) ---- */          \
    if (gact) {                                                                     \
        const unsigned short* xrow = &xh[(PA) * 32 + c][0];                         \
        _Pragma("unroll") for (int i = 0; i < 16; ++i) { acc[i] = breg[i]; accB[i] = 0.f; } \
        __builtin_amdgcn_s_setprio(1);                                              \
        _Pragma("unroll") for (int kt = 0; kt < 24; kt += 2) {                      \
            short8 b0 = *reinterpret_cast<const short8*>(xrow + kt * 16 + lh * 8);  \
            short8 b1 = *reinterpret_cast<const short8*>(xrow + (kt + 1) * 16 + lh * 8); \
            acc  = __builtin_amdgcn_mfma_f32_32x32x16_bf16(wreg[kt], b0, acc, 0, 0, 0); \
            accB = __builtin_amdgcn_mfma_f32_32x32x16_bf16(wreg[kt + 1], b1, accB, 0, 0, 0); \
        }                                                                           \
        __builtin_amdgcn_s_setprio(0);                                              \
        _Pragma("unroll") for (int i = 0; i < 16; ++i) acc[i] += accB[i];           \
    } else if (oact) {                                                              \
        if (to_ + 1 < TSTEPS) {                                                     \
            const float* sp = seq + ((size_t)(to_ + 1) * 2048 + row0 + PB_ * 32 + c) * 128 \
                            + hm * 32 + 4 * lh;                                     \
            _Pragma("unroll") for (int g = 0; g < 4; ++g)                           \
                sq[g] = *reinterpret_cast<const f32x4*>(sp + 8 * g);                \
        }                                                                           \
        unsigned int tgt = 32u * (unsigned)(to_ + 1);                               \
        while (__hip_atomic_load(cntP[PB_], __ATOMIC_RELAXED, __HIP_MEMORY_SCOPE_AGENT) < tgt) \
            __builtin_amdgcn_s_sleep(1);                                            \
        asm volatile("" ::: "memory");                                              \
        {                                                                           \
            const unsigned short* hsrc = hb + (size_t)(to_ & 1) * 524288 + (size_t)r * 16384; \
            int tid2 = tid & 255;                                                   \
            i32x4 hv[4];                                                            \
            _Pragma("unroll") for (int i2 = 0; i2 < 4; ++i2) {                      \
                int ch = i2 * 256 + tid2;                                           \
                hv[i2] = load_coh16(hsrc + (size_t)((PB_ * 32 + (ch >> 5)) * 256 + (ch & 31) * 8)); \
            }                                                                       \
            asm volatile("s_waitcnt vmcnt(0)" ::: "memory");                        \
            __builtin_amdgcn_sched_barrier(0);                                      \
            _Pragma("unroll") for (int i2 = 0; i2 < 4; ++i2) {                      \
                int ch = i2 * 256 + tid2;                                           \
                *reinterpret_cast<i32x4*>(&xh[PB_ * 32 + (ch >> 5)][128 + (ch & 31) * 8]) = hv[i2]; \
            }                                                                       \
        }                                                                           \
    }                                                                               \
    __syncthreads();   /* mid: ow restage visible to ow MFMA readers */             \
    /* ---- phase 2: gw LSTM+store+flag(PA)  ||  ow out-proj+epilogue(PB) ---- */   \
    if (gact) {                                                                     \
        float hn[4];                                                                \
        _Pragma("unroll") for (int g = 0; g < 4; ++g) {                             \
            float cn = sigf(acc[4 * g + 1]) * CSTA[g]                               \
                     + sigf(acc[4 * g + 0]) * tanh_fast(acc[4 * g + 2]);            \
            hn[g] = sigf(acc[4 * g + 3]) * tanh_fast(cn);                           \
            CSTA[g] = cn;                                                           \
        }                                                                           \
        i32x4 hw;                                                                   \
        _Pragma("unroll") for (int g = 0; g < 4; ++g) {                             \
            float other = __shfl_xor(hn[g], 32);                                    \
            unsigned short lo = f2bf(lh ? other : hn[g]);                           \
            unsigned short hi = f2bf(lh ? hn[g] : other);                           \
            hw[g] = (int)((unsigned)lo | ((unsigned)hi << 16));                     \
        }                                                                           \
        if (lh == 0) {                                                              \
            char* hp = (char*)hb + (size_t)(tg_ & 1) * 1048576 + (size_t)r * 32768  \
                     + (size_t)((PA) * 32 + c) * 512 + s * 64 + hm * 16;            \
            store_coh16(hp, hw);                                                    \
        }                                                                           \
        asm volatile("s_waitcnt vmcnt(0)" ::: "memory");                            \
        if (l == 0)                                                                 \
            __hip_atomic_fetch_add(cntP[PA], 1u, __ATOMIC_RELAXED, __HIP_MEMORY_SCOPE_AGENT); \
    } else if (oact) {                                                              \
        const unsigned short* xrow = &xh[PB_ * 32 + c][0];                          \
        _Pragma("unroll") for (int i = 0; i < 16; ++i) { acc[i] = breg[i]; accB[i] = 0.f; } \
        __builtin_amdgcn_s_setprio(1);                                              \
        _Pragma("unroll") for (int kt = 0; kt < 16; kt += 2) {                      \
            short8 b0 = *reinterpret_cast<const short8*>(xrow + 128 + kt * 16 + lh * 8); \
            short8 b1 = *reinterpret_cast<const short8*>(xrow + 128 + (kt + 1) * 16 + lh * 8); \
            acc  = __builtin_amdgcn_mfma_f32_32x32x16_bf16(wreg[kt], b0, acc, 0, 0, 0); \
            accB = __builtin_amdgcn_mfma_f32_32x32x16_bf16(wreg[kt + 1], b1, accB, 0, 0, 0); \
        }                                                                           \
        __builtin_amdgcn_s_setprio(0);                                              \
        float vv[16];                                                               \
        _Pragma("unroll") for (int g = 0; g < 4; ++g) {                             \
            _Pragma("unroll") for (int j = 0; j < 4; ++j) {                         \
                int i = 4 * g + j;                                                  \
                float v = acc[i] + accB[i];                                         \
                unsigned short x16 = (unsigned short)(XVB[2 * g + (j >> 1)] >> ((j & 1) * 16)); \
                bool isCat = (g == 0) && (j < 3) && hm0lh0;                         \
                if (!isCat) v += bf2f(x16);                                         \
                vv[i] = v;                                                          \
            }                                                                       \
        }                                                                           \
        if (hm0lh0) {                                                               \
            float mx = fmaxf(fmaxf(vv[0], vv[1]), vv[2]);                           \
            float e0 = __expf(vv[0] - mx), e1 = __expf(vv[1] - mx), e2 = __expf(vv[2] - mx); \
            float rs = __builtin_amdgcn_rcpf(e0 + e1 + e2);                         \
            vv[0] = e0 * rs; vv[1] = e1 * rs; vv[2] = e2 * rs;                      \
        }                                                                           \
        if (hm == (s >> 1)) {                                                       \
            int gp = (s & 1) * 2;                                                   \
            size_t ob0 = ((size_t)to_ * 2048 + row0 + PB_ * 32 + c) * 128 + hm * 32 + 4 * lh; \
            f32x4 o0 = {vv[4 * gp], vv[4 * gp + 1], vv[4 * gp + 2], vv[4 * gp + 3]}; \
            f32x4 o1 = {vv[4 * gp + 4], vv[4 * gp + 5], vv[4 * gp + 6], vv[4 * gp + 7]}; \
            *reinterpret_cast<f32x4*>(out + ob0 + 8 * gp) = o0;                     \
            *reinterpret_cast<f32x4*>(out + ob0 + 8 * gp + 8) = o1;                 \
        }                                                                           \
        if (to_ < TSTEPS - 1) {                                                     \
            _Pragma("unroll") for (int g = 0; g < 4; ++g) {                         \
                unsigned int w0 = 0, w1 = 0;                                        \
                _Pragma("unroll") for (int j = 0; j < 4; ++j) {                     \
                    float sqv = sq[g][j];                                           \
                    float xf = (sqv != sqv) ? vv[4 * g + j] : sqv;                  \
                    unsigned short nv = f2bf(xf);                                   \
                    if (j < 2) w0 |= (unsigned)nv << (16 * j);                      \
                    else       w1 |= (unsigned)nv << (16 * (j - 2));                \
                }                                                                   \
                XVB[2 * g] = w0; XVB[2 * g + 1] = w1;                               \
                u32x2 wp = {w0, w1};                                                \
                *reinterpret_cast<u32x2*>(&xh[PB_ * 32 + c][hm * 32 + 8 * g + 4 * lh]) = wp; \
            }                                                                       \
        }                                                                           \
    }                                                                               \
    __syncthreads();   /* boundary */                                               \
} while (0)

// ---------------------------------------------------------------------------
// Main persistent kernel: grid=256, 512 threads (1 WG/CU via VGPR + LDS pad).
// ---------------------------------------------------------------------------
__global__ __launch_bounds__(512, 2) void rnn_kernel(
    const float* __restrict__ seq,
    const unsigned short* __restrict__ Wg, const unsigned short* __restrict__ Wo,
    const float* __restrict__ bg, const float* __restrict__ bo,
    unsigned short* __restrict__ hb, unsigned int* __restrict__ flags,
    float* __restrict__ out) {

    __shared__ __align__(16) unsigned short xh[64][XROW];   // 50176 B
    __shared__ __align__(16) float bgl[128];
    __shared__ __align__(16) float obl[128];
    extern __shared__ char lds_pad[];
    (void)lds_pad;

    const int tid = threadIdx.x;
    const int wv  = tid >> 6, l = tid & 63;
    const int c   = l & 31, lh = l >> 5;
    const int s   = blockIdx.x >> 5;       // col slice 0..7
    const int r   = blockIdx.x & 31;       // row block 0..31
    const int row0 = r * 64;
    const bool isGW = wv < 4;              // waves 0-3: gates; 4-7: out-proj
    const int hm  = wv & 3;                // tile index within role
    const bool hm0lh0 = (hm == 0) && (lh == 0);

    unsigned int* cntP[2] = {flags + r * 32, flags + r * 32 + 16};

    // ---- persistent weight A-fragments in VGPRs (role-specialized) ----
    short8 wreg[24];
    if (isGW) {
        const short8* WgV = reinterpret_cast<const short8*>(Wg);
#pragma unroll
        for (int kt = 0; kt < 24; ++kt) wreg[kt] = WgV[(size_t)(((s * 4 + hm) * 24 + kt) * 64) + l];
    } else {
        const short8* WoV = reinterpret_cast<const short8*>(Wo);
#pragma unroll
        for (int kt = 0; kt < 16; ++kt) wreg[kt] = WoV[(size_t)((hm * 16 + kt) * 64) + l];
#pragma unroll
        for (int kt = 16; kt < 24; ++kt) wreg[kt] = wreg[0];
    }

    // ---- permuted biases -> LDS ----
    if (tid < 128) {
        int gm_ = tid >> 5, lh_ = (tid >> 4) & 1, i_ = tid & 15;
        int pm = (i_ & 3) + 8 * (i_ >> 2) + 4 * lh_;
        bgl[tid] = bg[(pm & 3) * 256 + s * 32 + gm_ * 8 + (pm >> 2)];
        obl[tid] = bo[gm_ * 32 + 8 * (i_ >> 2) + 4 * lh_ + (i_ & 3)];
    }

    // ---- x(0) = bf16(seq[0]) (NaN-free), h(0) = 0 ----
#pragma unroll
    for (int i = 0; i < 4; ++i) {
        int ch = i * 512 + tid;
        int row = ch >> 5, c4 = ch & 31;
        f32x4 v = *reinterpret_cast<const f32x4*>(seq + (size_t)(row0 + row) * 128 + c4 * 4);
        unsigned short* p = &xh[row][c4 * 4];
        p[0] = f2bf(v[0]); p[1] = f2bf(v[1]); p[2] = f2bf(v[2]); p[3] = f2bf(v[3]);
    }
    {
        short8 z = {0, 0, 0, 0, 0, 0, 0, 0};
#pragma unroll
        for (int i = 0; i < 4; ++i) {
            int ch = i * 512 + tid;
            *reinterpret_cast<short8*>(&xh[ch >> 5][128 + (ch & 31) * 8]) = z;
        }
    }

    // ---- reg-resident x(t) for out-waves (both sub-blocks), from seq[0] ----
    unsigned int xv0[8], xv1[8];
    if (!isGW) {
        const float* sp0 = seq + (size_t)(row0 + c) * 128 + hm * 32 + 4 * lh;
#pragma unroll
        for (int g = 0; g < 4; ++g) {
            f32x4 v = *reinterpret_cast<const f32x4*>(sp0 + 8 * g);
            xv0[2 * g]     = (unsigned)f2bf(v[0]) | ((unsigned)f2bf(v[1]) << 16);
            xv0[2 * g + 1] = (unsigned)f2bf(v[2]) | ((unsigned)f2bf(v[3]) << 16);
        }
        const float* sp1 = seq + (size_t)(row0 + 32 + c) * 128 + hm * 32 + 4 * lh;
#pragma unroll
        for (int g = 0; g < 4; ++g) {
            f32x4 v = *reinterpret_cast<const f32x4*>(sp1 + 8 * g);
            xv1[2 * g]     = (unsigned)f2bf(v[0]) | ((unsigned)f2bf(v[1]) << 16);
            xv1[2 * g + 1] = (unsigned)f2bf(v[2]) | ((unsigned)f2bf(v[3]) << 16);
        }
    }

    float cst0[4] = {0.f, 0.f, 0.f, 0.f};
    float cst1[4] = {0.f, 0.f, 0.f, 0.f};

    __syncthreads();

    float breg[16];
#pragma unroll
    for (int i = 0; i < 16; ++i)
        breg[i] = isGW ? bgl[(hm * 2 + lh) * 16 + i] : obl[(hm * 2 + lh) * 16 + i];

    for (int tt = 0; tt < TSTEPS; ++tt) {
        SLOT(0, tt, tt - 1, cst0, xv1);    // gw: P0 step tt   | ow: P1 step tt-1
        SLOT(1, tt, tt,     cst1, xv0);    // gw: P1 step tt   | ow: P0 step tt
    }
    SLOT(0, TSTEPS, TSTEPS - 1, cst0, xv1); // drain: ow P1 step TSTEPS-1
}

// ---------------------------------------------------------------------------
extern "C" void kernel_launch(void* const* d_in, const int* in_sizes, int n_in,
                              void* d_out, int out_size, void* d_ws, size_t ws_size,
                              hipStream_t stream) {
    const float* seq  = (const float*)d_in[0];
    const float* Wih  = (const float*)d_in[1];
    const float* Whh  = (const float*)d_in[2];
    const float* bih  = (const float*)d_in[3];
    const float* bhh  = (const float*)d_in[4];
    const float* Wcat = (const float*)d_in[5];
    const float* bcat = (const float*)d_in[6];
    const float* Wval = (const float*)d_in[7];
    const float* bval = (const float*)d_in[8];

    char* ws = (char*)d_ws;
    unsigned short* Wg    = (unsigned short*)(ws);                 //  786432 B
    unsigned short* Wo    = (unsigned short*)(ws + 786432);        //   65536 B
    float*          bgp   = (float*)(ws + 851968);                 //    4096 B
    float*          bop   = (float*)(ws + 856064);                 //     512 B
    unsigned int*   flags = (unsigned int*)(ws + 856576);          //    4096 B
    unsigned short* hbuf  = (unsigned short*)(ws + 860672);        // 2097152 B (2 parity buffers)
    // total ws use: 2957824 B

    prep_kernel<<<1673, 256, 0, stream>>>(Wih, Whh, bih, bhh, Wcat, bcat, Wval, bval,
                                          Wg, Wo, bgp, bop, flags);
    rnn_kernel<<<256, 512, 32768, stream>>>(seq, Wg, Wo, bgp, bop, hbuf, flags, (float*)d_out);
}